// Round 19
// baseline (229.965 us; speedup 1.0000x reference)
//
#include <hip/hip_runtime.h>

// PolyAttention on MI355X (gfx950).
// k_prep -> fused QKV GEMM (256x128, BK=32, 3-buffer, vmcnt(6), zero-conflict
// paired-row LDS, 32x32x16 MFMA, rope fused, V transposed) -> causal poly^4
// attention (dual-group 512thr, pair-balanced) -> output GEMM (128x128,
// 3-buffer, vmcnt(4), 16x16x32).  b=2, n=2048, d=2048, h=16, hd=128.

typedef __bf16 bf16;
typedef __bf16 bf16x8 __attribute__((ext_vector_type(8)));
typedef __bf16 bf16x4 __attribute__((ext_vector_type(4)));
typedef float f32x4 __attribute__((ext_vector_type(4)));
typedef float f32x16 __attribute__((ext_vector_type(16)));

#define GLD(g, l)                                                   \
  __builtin_amdgcn_global_load_lds(                                 \
      (const __attribute__((address_space(1))) void*)(g),           \
      (__attribute__((address_space(3))) void*)(l), 16, 0, 0)

#define MFMA(a, b, c) __builtin_amdgcn_mfma_f32_16x16x32_bf16(a, b, c, 0, 0, 0)
#define MFMA32(a, b, c) __builtin_amdgcn_mfma_f32_32x32x16_bf16(a, b, c, 0, 0, 0)

// ---------- fused prep: cvt x / wqkv / wo (f32->bf16) + rope cos/sin table ----
__global__ __launch_bounds__(256) void k_prep(
    const float* __restrict__ x, const float* __restrict__ Wq,
    const float* __restrict__ Wk, const float* __restrict__ Wv,
    const float* __restrict__ Wo, bf16* __restrict__ xb,
    bf16* __restrict__ wqkv, bf16* __restrict__ wob,
    float* __restrict__ ct, float* __restrict__ st) {
  const int b = blockIdx.x, tid = threadIdx.x;
  if (b < 8192) {
    int i = b * 256 + tid;
    float4 v = reinterpret_cast<const float4*>(x)[i];
    bf16x4 o = {(bf16)v.x, (bf16)v.y, (bf16)v.z, (bf16)v.w};
    reinterpret_cast<bf16x4*>(xb)[i] = o;
  } else if (b < 20480) {
    int i = (b - 8192) * 256 + tid;
    const float* src = (i < 1048576) ? Wq : ((i < 2097152) ? Wk : Wv);
    float4 v = reinterpret_cast<const float4*>(src)[i & 1048575];
    bf16x4 o = {(bf16)v.x, (bf16)v.y, (bf16)v.z, (bf16)v.w};
    reinterpret_cast<bf16x4*>(wqkv)[i] = o;
  } else if (b < 24576) {
    int i = (b - 20480) * 256 + tid;
    float4 v = reinterpret_cast<const float4*>(Wo)[i];
    bf16x4 o = {(bf16)v.x, (bf16)v.y, (bf16)v.z, (bf16)v.w};
    reinterpret_cast<bf16x4*>(wob)[i] = o;
  } else {
    int i = (b - 24576) * 256 + tid;
    int pos = i >> 6, f = i & 63;
    float theta = exp2f(-(float)f * 0.20762050593046014f);
    float ang = (float)pos * theta;
    ct[i] = cosf(ang);
    st[i] = sinf(ang);
  }
}

// ---------- fused QKV GEMM + rope epilogue (32x32x16 MFMA) ----------
// Same 3-buffer vmcnt(6) loop + zero-conflict paired-row LDS layout as r18.
// Per wave 128x64 = 4m x 2n blocks of 32x32; BK=32 = 2 ksteps of K=16.
// Fragment reads satisfy the distinct-chunk rule (conflict-free, verified
// against the measured-zero layout). C/D: col=lane&31,
// row=(reg&3)+8*(reg>>2)+4*(lane>>5)  [HW-verified m74/m101].
__global__ __launch_bounds__(256, 2) void k_gemm_qkv(
    const bf16* __restrict__ Am, const bf16* __restrict__ Bm,
    bf16* __restrict__ Qp, bf16* __restrict__ Kp, bf16* __restrict__ Vt,
    const float* __restrict__ ct, const float* __restrict__ st) {
  __shared__ __align__(16) char LDS[73728];  // 3 x (16KB A + 8KB B)
  const int tid = threadIdx.x, w = tid >> 6, l = tid & 63;
  const int wr = w >> 1, wc = w & 1;
  const int l31 = l & 31, hi = l >> 5;
  const int jrow = l31 >> 1, par = (l31 & 1) << 2;
  const int tm = blockIdx.y * 256, tn = blockIdx.x * 128;

  // staging source (inverse-swizzled) — unchanged layout
  const int clv = (tid & 7) ^ ((tid >> 3) & 7);
  const int srow = 2 * (tid >> 3) + (clv >> 2);
  const int scol = (clv & 3) * 8;
  // fragment read offsets: chunk (par + 2s + hi) ^ (jrow&7), s=kstep
  const int x0c = ((par + hi) ^ (jrow & 7)) << 4;
  const int x1c = x0c ^ 32;  // (par+hi)^2 flips bit1 of the chunk index
  const int rbase = jrow * 128;

#define STAGEQ(buf, kt)                                                      \
  {                                                                          \
    _Pragma("unroll") for (int i = 0; i < 4; ++i)                            \
        GLD(Am + (size_t)(tm + i * 64 + srow) * 2048 + (kt) + scol,          \
            LDS + (buf) * 24576 + i * 4096 + tid * 16);                      \
    _Pragma("unroll") for (int i = 0; i < 2; ++i)                            \
        GLD(Bm + (size_t)(tn + i * 64 + srow) * 2048 + (kt) + scol,          \
            LDS + (buf) * 24576 + 16384 + i * 4096 + tid * 16);              \
  }

  f32x16 acc[4][2] = {};

  STAGEQ(0, 0);
  STAGEQ(1, 32);
  int cur = 0, st3 = 2;
  for (int t = 0; t < 63; ++t) {
    asm volatile("s_waitcnt vmcnt(6)" ::: "memory");
    __builtin_amdgcn_s_barrier();
    asm volatile("" ::: "memory");
    const char* pa = LDS + cur * 24576;
    const char* pb = pa + 16384;
    bf16x8 a[4], b[2];
    // kstep 0
#pragma unroll
    for (int mb = 0; mb < 4; ++mb)
      a[mb] = *reinterpret_cast<const bf16x8*>(pa + wr * 8192 + mb * 2048 + rbase + x0c);
#pragma unroll
    for (int nb = 0; nb < 2; ++nb)
      b[nb] = *reinterpret_cast<const bf16x8*>(pb + wc * 4096 + nb * 2048 + rbase + x0c);
    if (t < 62) STAGEQ(st3, (t + 2) * 32);
    __builtin_amdgcn_s_setprio(1);
#pragma unroll
    for (int mb = 0; mb < 4; ++mb)
#pragma unroll
      for (int nb = 0; nb < 2; ++nb)
        acc[mb][nb] = MFMA32(a[mb], b[nb], acc[mb][nb]);
    __builtin_amdgcn_s_setprio(0);
    // kstep 1
#pragma unroll
    for (int mb = 0; mb < 4; ++mb)
      a[mb] = *reinterpret_cast<const bf16x8*>(pa + wr * 8192 + mb * 2048 + rbase + x1c);
#pragma unroll
    for (int nb = 0; nb < 2; ++nb)
      b[nb] = *reinterpret_cast<const bf16x8*>(pb + wc * 4096 + nb * 2048 + rbase + x1c);
    __builtin_amdgcn_s_setprio(1);
#pragma unroll
    for (int mb = 0; mb < 4; ++mb)
#pragma unroll
      for (int nb = 0; nb < 2; ++nb)
        acc[mb][nb] = MFMA32(a[mb], b[nb], acc[mb][nb]);
    __builtin_amdgcn_s_setprio(0);
    cur = (cur == 2) ? 0 : cur + 1;
    st3 = (st3 == 2) ? 0 : st3 + 1;
  }
  {  // peeled last tile
    asm volatile("s_waitcnt vmcnt(0)" ::: "memory");
    __builtin_amdgcn_s_barrier();
    asm volatile("" ::: "memory");
    const char* pa = LDS + cur * 24576;
    const char* pb = pa + 16384;
    bf16x8 a[4], b[2];
#pragma unroll
    for (int s = 0; s < 2; ++s) {
      const int xs = s ? x1c : x0c;
#pragma unroll
      for (int mb = 0; mb < 4; ++mb)
        a[mb] = *reinterpret_cast<const bf16x8*>(pa + wr * 8192 + mb * 2048 + rbase + xs);
#pragma unroll
      for (int nb = 0; nb < 2; ++nb)
        b[nb] = *reinterpret_cast<const bf16x8*>(pb + wc * 4096 + nb * 2048 + rbase + xs);
#pragma unroll
      for (int mb = 0; mb < 4; ++mb)
#pragma unroll
        for (int nb = 0; nb < 2; ++nb)
          acc[mb][nb] = MFMA32(a[mb], b[nb], acc[mb][nb]);
    }
  }

  if (tn < 4096) {
    __syncthreads();
    bf16* E = (bf16*)LDS;  // [256][136]
#pragma unroll
    for (int mb = 0; mb < 4; ++mb)
#pragma unroll
      for (int nb = 0; nb < 2; ++nb)
#pragma unroll
        for (int rr = 0; rr < 16; ++rr) {
          int row = wr * 128 + mb * 32 + (rr & 3) + ((rr >> 2) << 3) + (hi << 2);
          int col = wc * 64 + nb * 32 + l31;
          E[row * 136 + col] = (bf16)acc[mb][nb][rr];
        }
    __syncthreads();
    const int hh = (tn & 2047) >> 7;
    bf16* dst = (tn < 2048) ? Qp : Kp;
#pragma unroll
    for (int i = 0; i < 16; ++i) {
      int task = i * 256 + tid;
      int row = task >> 4, dg = (task & 15) << 2;
      int token = tm + row, nn = token & 2047, bb = token >> 11;
      f32x4 c4 = *reinterpret_cast<const f32x4*>(ct + nn * 64 + dg);
      f32x4 s4 = *reinterpret_cast<const f32x4*>(st + nn * 64 + dg);
      bf16x4 x1 = *reinterpret_cast<const bf16x4*>(E + row * 136 + dg);
      bf16x4 x2 = *reinterpret_cast<const bf16x4*>(E + row * 136 + 64 + dg);
      bf16x4 o1, o2;
#pragma unroll
      for (int j = 0; j < 4; ++j) {
        float a1 = (float)x1[j], a2 = (float)x2[j];
        o1[j] = (bf16)(a1 * c4[j] - a2 * s4[j]);
        o2[j] = (bf16)(a1 * s4[j] + a2 * c4[j]);
      }
      size_t rbo = (((size_t)bb * 16 + hh) * 2048 + nn) * 128;
      *reinterpret_cast<bf16x4*>(dst + rbo + dg) = o1;
      *reinterpret_cast<bf16x4*>(dst + rbo + 64 + dg) = o2;
    }
  } else {
    // V transposed: regs 4q..4q+3 are 4 consecutive token rows
#pragma unroll
    for (int mb = 0; mb < 4; ++mb)
#pragma unroll
      for (int nb = 0; nb < 2; ++nb)
#pragma unroll
        for (int q = 0; q < 4; ++q) {
          int row0 = tm + wr * 128 + mb * 32 + q * 8 + hi * 4;
          int col = (tn - 4096) + wc * 64 + nb * 32 + l31;
          int bb = row0 >> 11, nn = row0 & 2047;
          int hh = col >> 7, dd = col & 127;
          bf16x4 o = {(bf16)acc[mb][nb][q * 4 + 0], (bf16)acc[mb][nb][q * 4 + 1],
                      (bf16)acc[mb][nb][q * 4 + 2], (bf16)acc[mb][nb][q * 4 + 3]};
          *reinterpret_cast<bf16x4*>(
              Vt + (((size_t)bb * 16 + hh) * 128 + dd) * 2048 + nn) = o;
        }
  }
}

// ---------- output GEMM: C(f32) = A*B^T (round-18 version, frozen) ----------
__global__ __launch_bounds__(256, 3) void k_gemm_out(const bf16* __restrict__ Am,
                                                     const bf16* __restrict__ Bm,
                                                     float* __restrict__ C) {
  __shared__ __align__(16) char LDS[49152];  // 3 x (8KB A + 8KB B)
  const int tid = threadIdx.x, w = tid >> 6, l = tid & 63;
  const int lr = l & 15, g = l >> 4;
  const int wr = w >> 1, wc = w & 1;
  const int tm = blockIdx.y * 128, tn = blockIdx.x * 128;

  const int clv = (tid & 7) ^ ((tid >> 3) & 7);
  const int srow = 2 * (tid >> 3) + (clv >> 2);
  const int scol = (clv & 3) * 8;
  const int cp = ((((lr & 1) << 2) | g) ^ ((lr >> 1) & 7)) << 4;
  const int rb = (lr >> 1) * 128 + cp;

#define STAGEO(buf, kt)                                                      \
  {                                                                          \
    _Pragma("unroll") for (int i = 0; i < 2; ++i)                            \
        GLD(Am + (size_t)(tm + i * 64 + srow) * 2048 + (kt) + scol,          \
            LDS + (buf) * 16384 + i * 4096 + tid * 16);                      \
    _Pragma("unroll") for (int i = 0; i < 2; ++i)                            \
        GLD(Bm + (size_t)(tn + i * 64 + srow) * 2048 + (kt) + scol,          \
            LDS + (buf) * 16384 + 8192 + i * 4096 + tid * 16);               \
  }

  f32x4 acc[4][4] = {};

  STAGEO(0, 0);
  STAGEO(1, 32);
  int cur = 0, st3 = 2;
  for (int t = 0; t < 63; ++t) {
    asm volatile("s_waitcnt vmcnt(4)" ::: "memory");
    __builtin_amdgcn_s_barrier();
    asm volatile("" ::: "memory");
    if (t < 62) STAGEO(st3, (t + 2) * 32);
    const char* pa = LDS + cur * 16384;
    const char* pb = pa + 8192;
    bf16x8 a[4], b[4];
#pragma unroll
    for (int fm = 0; fm < 4; ++fm)
      a[fm] = *reinterpret_cast<const bf16x8*>(pa + wr * 4096 + fm * 1024 + rb);
#pragma unroll
    for (int nf = 0; nf < 4; ++nf)
      b[nf] = *reinterpret_cast<const bf16x8*>(pb + wc * 4096 + nf * 1024 + rb);
    __builtin_amdgcn_s_setprio(1);
#pragma unroll
    for (int fm = 0; fm < 4; ++fm)
#pragma unroll
      for (int nf = 0; nf < 4; ++nf)
        acc[fm][nf] = MFMA(a[fm], b[nf], acc[fm][nf]);
    __builtin_amdgcn_s_setprio(0);
    cur = (cur == 2) ? 0 : cur + 1;
    st3 = (st3 == 2) ? 0 : st3 + 1;
  }
  {
    asm volatile("s_waitcnt vmcnt(0)" ::: "memory");
    __builtin_amdgcn_s_barrier();
    asm volatile("" ::: "memory");
    const char* pa = LDS + cur * 16384;
    const char* pb = pa + 8192;
    bf16x8 a[4], b[4];
#pragma unroll
    for (int fm = 0; fm < 4; ++fm)
      a[fm] = *reinterpret_cast<const bf16x8*>(pa + wr * 4096 + fm * 1024 + rb);
#pragma unroll
    for (int nf = 0; nf < 4; ++nf)
      b[nf] = *reinterpret_cast<const bf16x8*>(pb + wc * 4096 + nf * 1024 + rb);
#pragma unroll
    for (int fm = 0; fm < 4; ++fm)
#pragma unroll
      for (int nf = 0; nf < 4; ++nf)
        acc[fm][nf] = MFMA(a[fm], b[nf], acc[fm][nf]);
  }

#pragma unroll
  for (int fm = 0; fm < 4; ++fm)
#pragma unroll
    for (int nf = 0; nf < 4; ++nf)
#pragma unroll
      for (int rr = 0; rr < 4; ++rr) {
        int row = tm + wr * 64 + fm * 16 + g * 4 + rr;
        int col = tn + wc * 64 + nf * 16 + lr;
        C[(size_t)row * 2048 + col] = acc[fm][nf][rr];
      }
}

// ---------- causal poly^4 attention (dual-group, pair-balanced; frozen) ----------
__global__ __launch_bounds__(512) void k_attn(const bf16* __restrict__ Q,
                                              const bf16* __restrict__ K,
                                              const bf16* __restrict__ Vt,
                                              bf16* __restrict__ O) {
  __shared__ __align__(16) char LDSC[131072];
  const int tid = threadIdx.x, w = tid >> 6, l = tid & 63;
  const int wg = w & 3, gp = w >> 2;
  const int lr = l & 15, g = l >> 4;
  const int pair = blockIdx.x >> 5;  // 0..7
  const int bh = blockIdx.x & 31;
  const size_t base = (size_t)bh * 2048 * 128;
  const int b_ = bh >> 4, h_ = bh & 15;
  const int GB = gp * 65536;

  bf16x8 vones = {};
  if (lr == 0) {
#pragma unroll
    for (int j = 0; j < 8; ++j) vones[j] = (bf16)1.0f;
  }

#define STAGE_K(tt, buf)                                                  \
  {                                                                       \
    const bf16* kg = K + base + (size_t)(tt) * 64 * 128;                  \
    _Pragma("unroll") for (int r = 0; r < 4; ++r) {                       \
      int row = r * 16 + wg * 4 + (l >> 4);                               \
      int cc = l & 15;                                                    \
      GLD(kg + (row << 7) + ((cc ^ (row & 7)) << 3),                      \
          LDSC + GB + (buf) * 16384 + r * 4096 + wg * 1024);              \
    }                                                                     \
  }
#define STAGE_V(tt)                                                       \
  {                                                                       \
    const bf16* vg = Vt + base + (tt) * 64;                               \
    _Pragma("unroll") for (int r = 0; r < 4; ++r) {                       \
      int row = r * 32 + wg * 8 + (l >> 3);                               \
      int cc = l & 7;                                                     \
      GLD(vg + (size_t)row * 2048 + ((cc ^ (row & 7)) << 3),              \
          LDSC + GB + 32768 + r * 4096 + wg * 1024);                      \
    }                                                                     \
  }

  for (int seg = 0; seg < 2; ++seg) {
    const int qb = seg ? (15 - pair) : pair;
    const int qbase = qb * 128;
    const int nh = qb + 1;

    bf16x8 qf[2][4];
#pragma unroll
    for (int mi = 0; mi < 2; ++mi)
#pragma unroll
      for (int kc = 0; kc < 4; ++kc)
        qf[mi][kc] = *reinterpret_cast<const bf16x8*>(
            Q + base + (size_t)(qbase + wg * 32 + mi * 16 + lr) * 128 + kc * 32 + g * 8);

    f32x4 on[2][8] = {};
    f32x4 dn4[2] = {};

    __builtin_amdgcn_s_barrier();
    STAGE_K(gp, 0);

    for (int j = 0; j < nh; ++j) {
      const int t = 2 * j + gp;
      const int tnx = (j + 1 < nh) ? t + 2 : t;
      STAGE_V(t);
      STAGE_K(tnx, (j + 1) & 1);
      asm volatile("s_waitcnt vmcnt(8)" ::: "memory");
      __builtin_amdgcn_s_barrier();  // BAR1

      const bf16* kcur = (const bf16*)(LDSC + GB + (j & 1) * 16384);
      const bf16* vcur = (const bf16*)(LDSC + GB + 32768);
      bf16* Ps = (bf16*)(LDSC + GB + 49152);

      f32x4 s[2][4] = {};
      __builtin_amdgcn_s_setprio(1);
#pragma unroll
      for (int kc = 0; kc < 4; ++kc) {
        bf16x8 kb[4];
#pragma unroll
        for (int ni = 0; ni < 4; ++ni)
          kb[ni] = *reinterpret_cast<const bf16x8*>(
              kcur + ((ni * 16 + lr) << 7) + (((kc * 4 + g) ^ (lr & 7)) << 3));
#pragma unroll
        for (int mi = 0; mi < 2; ++mi)
#pragma unroll
          for (int ni = 0; ni < 4; ++ni)
            s[mi][ni] = MFMA(qf[mi][kc], kb[ni], s[mi][ni]);
      }
      __builtin_amdgcn_s_setprio(0);

#pragma unroll
      for (int mi = 0; mi < 2; ++mi) {
        const bool msk = (t * 64 + 63 > qbase + wg * 32 + mi * 16);
#pragma unroll
        for (int ni = 0; ni < 4; ++ni)
#pragma unroll
          for (int r = 0; r < 4; ++r) {
            int lrow = mi * 16 + g * 4 + r;
            float v = s[mi][ni][r];
            if (msk) {
              int qrow = qbase + wg * 32 + lrow;
              int col = t * 64 + ni * 16 + lr;
              v = (col <= qrow) ? v : 0.f;
            }
            float v2 = v * v, v4 = v2 * v2;
            Ps[((wg * 32 + lrow) << 6) +
               (((ni * 2 + (lr >> 3)) ^ (lrow & 7)) << 3) + (lr & 7)] = (bf16)v4;
          }
      }

      asm volatile("s_waitcnt vmcnt(4)" ::: "memory");
      __builtin_amdgcn_s_barrier();  // BAR2

      __builtin_amdgcn_s_setprio(1);
#pragma unroll
      for (int k2 = 0; k2 < 2; ++k2) {
        bf16x8 pa[2];
#pragma unroll
        for (int mi = 0; mi < 2; ++mi)
          pa[mi] = *reinterpret_cast<const bf16x8*>(
              Ps + ((wg * 32 + mi * 16 + lr) << 6) + (((k2 * 4 + g) ^ (lr & 7)) << 3));
        dn4[0] = MFMA(pa[0], vones, dn4[0]);
        dn4[1] = MFMA(pa[1], vones, dn4[1]);
#pragma unroll
        for (int ni = 0; ni < 8; ++ni) {
          bf16x8 vbf = *reinterpret_cast<const bf16x8*>(
              vcur + ((ni * 16 + lr) << 6) + (((k2 * 4 + g) ^ (lr & 7)) << 3));
          on[0][ni] = MFMA(pa[0], vbf, on[0][ni]);
          on[1][ni] = MFMA(pa[1], vbf, on[1][ni]);
        }
      }
      __builtin_amdgcn_s_setprio(0);
      __builtin_amdgcn_s_barrier();  // BAR3
    }

    asm volatile("s_waitcnt vmcnt(0)" ::: "memory");
    __builtin_amdgcn_s_barrier();

    if (gp == 1) {
      f32x4* dst = (f32x4*)(LDSC + (size_t)(tid & 255) * 288);
#pragma unroll
      for (int mi = 0; mi < 2; ++mi)
#pragma unroll
        for (int ni = 0; ni < 8; ++ni) dst[mi * 8 + ni] = on[mi][ni];
      dst[16] = dn4[0];
      dst[17] = dn4[1];
    }
    __builtin_amdgcn_s_barrier();
    if (gp == 0) {
      const f32x4* src = (const f32x4*)(LDSC + (size_t)tid * 288);
#pragma unroll
      for (int mi = 0; mi < 2; ++mi)
#pragma unroll
        for (int ni = 0; ni < 8; ++ni) on[mi][ni] += src[mi * 8 + ni];
      dn4[0] += src[16];
      dn4[1] += src[17];
#pragma unroll
      for (int mi = 0; mi < 2; ++mi)
#pragma unroll
        for (int r = 0; r < 4; ++r) {
          float d = __shfl(dn4[mi][r], l & 48);
          float inv = 1.0f / fmaxf(d, 1e-6f);
          int row = qbase + wg * 32 + mi * 16 + g * 4 + r;
#pragma unroll
          for (int ni = 0; ni < 8; ++ni)
            O[((size_t)b_ * 2048 + row) * 2048 + h_ * 128 + ni * 16 + lr] =
                (bf16)(on[mi][ni][r] * inv);
        }
    }
  }
#undef STAGE_K
#undef STAGE_V
}

extern "C" void kernel_launch(void* const* d_in, const int* in_sizes, int n_in,
                              void* d_out, int out_size, void* d_ws, size_t ws_size,
                              hipStream_t stream) {
  const float* x  = (const float*)d_in[0];
  const float* Wq = (const float*)d_in[1];
  const float* Wk = (const float*)d_in[2];
  const float* Wv = (const float*)d_in[3];
  const float* Wo = (const float*)d_in[4];
  float* out = (float*)d_out;

  char* p = (char*)d_ws;
  bf16* xb   = (bf16*)p; p += (size_t)8388608 * 2;
  bf16* wqkv = (bf16*)p; p += (size_t)12582912 * 2;
  bf16* wob  = (bf16*)p; p += (size_t)4194304 * 2;
  bf16* Qp   = (bf16*)p; p += (size_t)8388608 * 2;
  bf16* Kp   = (bf16*)p; p += (size_t)8388608 * 2;
  bf16* Vt   = (bf16*)p; p += (size_t)8388608 * 2;
  bf16* Ob   = (bf16*)p; p += (size_t)8388608 * 2;
  float* ct  = (float*)p; p += (size_t)131072 * 4;
  float* st  = (float*)p; p += (size_t)131072 * 4;

  k_prep<<<25088, 256, 0, stream>>>(x, Wq, Wk, Wv, Wo, xb, wqkv, wob, ct, st);

  k_gemm_qkv<<<dim3(48, 16), 256, 0, stream>>>(xb, wqkv, Qp, Kp, Vt, ct, st);

  k_attn<<<256, 512, 0, stream>>>(Qp, Kp, Vt, Ob);

  k_gemm_out<<<dim3(16, 32), 256, 0, stream>>>(Ob, wob, out);
}

// Round 20
// 224.256 us; speedup vs baseline: 1.0255x; 1.0255x over previous
//
#include <hip/hip_runtime.h>

// PolyAttention on MI355X (gfx950).  ROUND-18 BEST STATE (224.4 us), reverted
// after the 32x32x16 MFMA experiment regressed (conflict analysis wrong:
// 9.4M conflicts returned, 114->125us).
// k_prep -> fused QKV GEMM (256x128, BK=32, 3-buffer, vmcnt(6), ZERO-CONFLICT
// paired-row LDS layout, rope fused, V transposed) -> causal poly^4 attention
// (dual-group 512thr, pair-balanced) -> output GEMM (128x128, 3-buffer,
// vmcnt(4), same layout).  b=2, n=2048, d=2048, h=16, hd=128.

typedef __bf16 bf16;
typedef __bf16 bf16x8 __attribute__((ext_vector_type(8)));
typedef __bf16 bf16x4 __attribute__((ext_vector_type(4)));
typedef float f32x4 __attribute__((ext_vector_type(4)));

#define GLD(g, l)                                                   \
  __builtin_amdgcn_global_load_lds(                                 \
      (const __attribute__((address_space(1))) void*)(g),           \
      (__attribute__((address_space(3))) void*)(l), 16, 0, 0)

#define MFMA(a, b, c) __builtin_amdgcn_mfma_f32_16x16x32_bf16(a, b, c, 0, 0, 0)

// ---------- fused prep: cvt x / wqkv / wo (f32->bf16) + rope cos/sin table ----
__global__ __launch_bounds__(256) void k_prep(
    const float* __restrict__ x, const float* __restrict__ Wq,
    const float* __restrict__ Wk, const float* __restrict__ Wv,
    const float* __restrict__ Wo, bf16* __restrict__ xb,
    bf16* __restrict__ wqkv, bf16* __restrict__ wob,
    float* __restrict__ ct, float* __restrict__ st) {
  const int b = blockIdx.x, tid = threadIdx.x;
  if (b < 8192) {
    int i = b * 256 + tid;
    float4 v = reinterpret_cast<const float4*>(x)[i];
    bf16x4 o = {(bf16)v.x, (bf16)v.y, (bf16)v.z, (bf16)v.w};
    reinterpret_cast<bf16x4*>(xb)[i] = o;
  } else if (b < 20480) {
    int i = (b - 8192) * 256 + tid;
    const float* src = (i < 1048576) ? Wq : ((i < 2097152) ? Wk : Wv);
    float4 v = reinterpret_cast<const float4*>(src)[i & 1048575];
    bf16x4 o = {(bf16)v.x, (bf16)v.y, (bf16)v.z, (bf16)v.w};
    reinterpret_cast<bf16x4*>(wqkv)[i] = o;
  } else if (b < 24576) {
    int i = (b - 20480) * 256 + tid;
    float4 v = reinterpret_cast<const float4*>(Wo)[i];
    bf16x4 o = {(bf16)v.x, (bf16)v.y, (bf16)v.z, (bf16)v.w};
    reinterpret_cast<bf16x4*>(wob)[i] = o;
  } else {
    int i = (b - 24576) * 256 + tid;
    int pos = i >> 6, f = i & 63;
    float theta = exp2f(-(float)f * 0.20762050593046014f);
    float ang = (float)pos * theta;
    ct[i] = cosf(ang);
    st[i] = sinf(ang);
  }
}

// ---------- fused QKV GEMM + rope epilogue ----------
// Round-4 loop structure (3-buffer, vmcnt(6) counted gates) with the
// ZERO-CONFLICT LDS layout: LDS row j (128B) holds tile rows {2j,2j+1} as
// 8 chunks of 16B; chunk c = (parity<<2)|quarter, physical = c ^ (j&7).
// Stage = linear dest + inverse-swizzled source (rule 21).
__global__ __launch_bounds__(256, 2) void k_gemm_qkv(
    const bf16* __restrict__ Am, const bf16* __restrict__ Bm,
    bf16* __restrict__ Qp, bf16* __restrict__ Kp, bf16* __restrict__ Vt,
    const float* __restrict__ ct, const float* __restrict__ st) {
  __shared__ __align__(16) char LDS[73728];  // 3 x (16KB A + 8KB B)
  const int tid = threadIdx.x, w = tid >> 6, l = tid & 63;
  const int lr = l & 15, g = l >> 4;
  const int wr = w >> 1, wc = w & 1;
  const int tm = blockIdx.y * 256, tn = blockIdx.x * 128;

  // staging source (inverse-swizzled)
  const int clv = (tid & 7) ^ ((tid >> 3) & 7);
  const int srow = 2 * (tid >> 3) + (clv >> 2);
  const int scol = (clv & 3) * 8;
  // ds-read: row base + swizzled chunk (constant per thread)
  const int cp = ((((lr & 1) << 2) | g) ^ ((lr >> 1) & 7)) << 4;
  const int rb = (lr >> 1) * 128 + cp;

#define STAGEQ(buf, kt)                                                      \
  {                                                                          \
    _Pragma("unroll") for (int i = 0; i < 4; ++i)                            \
        GLD(Am + (size_t)(tm + i * 64 + srow) * 2048 + (kt) + scol,          \
            LDS + (buf) * 24576 + i * 4096 + tid * 16);                      \
    _Pragma("unroll") for (int i = 0; i < 2; ++i)                            \
        GLD(Bm + (size_t)(tn + i * 64 + srow) * 2048 + (kt) + scol,          \
            LDS + (buf) * 24576 + 16384 + i * 4096 + tid * 16);              \
  }

  f32x4 acc[8][4] = {};

  STAGEQ(0, 0);
  STAGEQ(1, 32);
  int cur = 0, st3 = 2;
  for (int t = 0; t < 63; ++t) {
    asm volatile("s_waitcnt vmcnt(6)" ::: "memory");
    __builtin_amdgcn_s_barrier();
    asm volatile("" ::: "memory");
    if (t < 62) STAGEQ(st3, (t + 2) * 32);
    const char* pa = LDS + cur * 24576;
    const char* pb = pa + 16384;
    bf16x8 a[8], b[4];
#pragma unroll
    for (int fm = 0; fm < 8; ++fm)
      a[fm] = *reinterpret_cast<const bf16x8*>(pa + wr * 8192 + fm * 1024 + rb);
#pragma unroll
    for (int nf = 0; nf < 4; ++nf)
      b[nf] = *reinterpret_cast<const bf16x8*>(pb + wc * 4096 + nf * 1024 + rb);
    __builtin_amdgcn_s_setprio(1);
#pragma unroll
    for (int fm = 0; fm < 8; ++fm)
#pragma unroll
      for (int nf = 0; nf < 4; ++nf)
        acc[fm][nf] = MFMA(a[fm], b[nf], acc[fm][nf]);
    __builtin_amdgcn_s_setprio(0);
    cur = (cur == 2) ? 0 : cur + 1;
    st3 = (st3 == 2) ? 0 : st3 + 1;
  }
  {  // peeled last tile
    asm volatile("s_waitcnt vmcnt(0)" ::: "memory");
    __builtin_amdgcn_s_barrier();
    asm volatile("" ::: "memory");
    const char* pa = LDS + cur * 24576;
    const char* pb = pa + 16384;
    bf16x8 a[8], b[4];
#pragma unroll
    for (int fm = 0; fm < 8; ++fm)
      a[fm] = *reinterpret_cast<const bf16x8*>(pa + wr * 8192 + fm * 1024 + rb);
#pragma unroll
    for (int nf = 0; nf < 4; ++nf)
      b[nf] = *reinterpret_cast<const bf16x8*>(pb + wc * 4096 + nf * 1024 + rb);
#pragma unroll
    for (int fm = 0; fm < 8; ++fm)
#pragma unroll
      for (int nf = 0; nf < 4; ++nf)
        acc[fm][nf] = MFMA(a[fm], b[nf], acc[fm][nf]);
  }

  if (tn < 4096) {
    __syncthreads();
    bf16* E = (bf16*)LDS;  // [256][136]
#pragma unroll
    for (int fm = 0; fm < 8; ++fm)
#pragma unroll
      for (int nf = 0; nf < 4; ++nf)
#pragma unroll
        for (int rr = 0; rr < 4; ++rr)
          E[(wr * 128 + fm * 16 + g * 4 + rr) * 136 + wc * 64 + nf * 16 + lr] =
              (bf16)acc[fm][nf][rr];
    __syncthreads();
    const int hh = (tn & 2047) >> 7;
    bf16* dst = (tn < 2048) ? Qp : Kp;
#pragma unroll
    for (int i = 0; i < 16; ++i) {
      int task = i * 256 + tid;
      int row = task >> 4, dg = (task & 15) << 2;
      int token = tm + row, nn = token & 2047, bb = token >> 11;
      f32x4 c4 = *reinterpret_cast<const f32x4*>(ct + nn * 64 + dg);
      f32x4 s4 = *reinterpret_cast<const f32x4*>(st + nn * 64 + dg);
      bf16x4 x1 = *reinterpret_cast<const bf16x4*>(E + row * 136 + dg);
      bf16x4 x2 = *reinterpret_cast<const bf16x4*>(E + row * 136 + 64 + dg);
      bf16x4 o1, o2;
#pragma unroll
      for (int j = 0; j < 4; ++j) {
        float a1 = (float)x1[j], a2 = (float)x2[j];
        o1[j] = (bf16)(a1 * c4[j] - a2 * s4[j]);
        o2[j] = (bf16)(a1 * s4[j] + a2 * c4[j]);
      }
      size_t rbo = (((size_t)bb * 16 + hh) * 2048 + nn) * 128;
      *reinterpret_cast<bf16x4*>(dst + rbo + dg) = o1;
      *reinterpret_cast<bf16x4*>(dst + rbo + 64 + dg) = o2;
    }
  } else {
#pragma unroll
    for (int fm = 0; fm < 8; ++fm)
#pragma unroll
      for (int nf = 0; nf < 4; ++nf) {
        int row0 = tm + wr * 128 + fm * 16 + g * 4;
        int col = (tn - 4096) + wc * 64 + nf * 16 + lr;
        int bb = row0 >> 11, nn = row0 & 2047;
        int hh = col >> 7, dd = col & 127;
        bf16x4 o = {(bf16)acc[fm][nf][0], (bf16)acc[fm][nf][1],
                    (bf16)acc[fm][nf][2], (bf16)acc[fm][nf][3]};
        *reinterpret_cast<bf16x4*>(
            Vt + (((size_t)bb * 16 + hh) * 128 + dd) * 2048 + nn) = o;
      }
  }
}

// ---------- output GEMM: C(f32) = A*B^T (round-4 structure + layout) ----------
__global__ __launch_bounds__(256, 3) void k_gemm_out(const bf16* __restrict__ Am,
                                                     const bf16* __restrict__ Bm,
                                                     float* __restrict__ C) {
  __shared__ __align__(16) char LDS[49152];  // 3 x (8KB A + 8KB B)
  const int tid = threadIdx.x, w = tid >> 6, l = tid & 63;
  const int lr = l & 15, g = l >> 4;
  const int wr = w >> 1, wc = w & 1;
  const int tm = blockIdx.y * 128, tn = blockIdx.x * 128;

  const int clv = (tid & 7) ^ ((tid >> 3) & 7);
  const int srow = 2 * (tid >> 3) + (clv >> 2);
  const int scol = (clv & 3) * 8;
  const int cp = ((((lr & 1) << 2) | g) ^ ((lr >> 1) & 7)) << 4;
  const int rb = (lr >> 1) * 128 + cp;

#define STAGEO(buf, kt)                                                      \
  {                                                                          \
    _Pragma("unroll") for (int i = 0; i < 2; ++i)                            \
        GLD(Am + (size_t)(tm + i * 64 + srow) * 2048 + (kt) + scol,          \
            LDS + (buf) * 16384 + i * 4096 + tid * 16);                      \
    _Pragma("unroll") for (int i = 0; i < 2; ++i)                            \
        GLD(Bm + (size_t)(tn + i * 64 + srow) * 2048 + (kt) + scol,          \
            LDS + (buf) * 16384 + 8192 + i * 4096 + tid * 16);               \
  }

  f32x4 acc[4][4] = {};

  STAGEO(0, 0);
  STAGEO(1, 32);
  int cur = 0, st3 = 2;
  for (int t = 0; t < 63; ++t) {
    asm volatile("s_waitcnt vmcnt(4)" ::: "memory");
    __builtin_amdgcn_s_barrier();
    asm volatile("" ::: "memory");
    if (t < 62) STAGEO(st3, (t + 2) * 32);
    const char* pa = LDS + cur * 16384;
    const char* pb = pa + 8192;
    bf16x8 a[4], b[4];
#pragma unroll
    for (int fm = 0; fm < 4; ++fm)
      a[fm] = *reinterpret_cast<const bf16x8*>(pa + wr * 4096 + fm * 1024 + rb);
#pragma unroll
    for (int nf = 0; nf < 4; ++nf)
      b[nf] = *reinterpret_cast<const bf16x8*>(pb + wc * 4096 + nf * 1024 + rb);
    __builtin_amdgcn_s_setprio(1);
#pragma unroll
    for (int fm = 0; fm < 4; ++fm)
#pragma unroll
      for (int nf = 0; nf < 4; ++nf)
        acc[fm][nf] = MFMA(a[fm], b[nf], acc[fm][nf]);
    __builtin_amdgcn_s_setprio(0);
    cur = (cur == 2) ? 0 : cur + 1;
    st3 = (st3 == 2) ? 0 : st3 + 1;
  }
  {
    asm volatile("s_waitcnt vmcnt(0)" ::: "memory");
    __builtin_amdgcn_s_barrier();
    asm volatile("" ::: "memory");
    const char* pa = LDS + cur * 16384;
    const char* pb = pa + 8192;
    bf16x8 a[4], b[4];
#pragma unroll
    for (int fm = 0; fm < 4; ++fm)
      a[fm] = *reinterpret_cast<const bf16x8*>(pa + wr * 4096 + fm * 1024 + rb);
#pragma unroll
    for (int nf = 0; nf < 4; ++nf)
      b[nf] = *reinterpret_cast<const bf16x8*>(pb + wc * 4096 + nf * 1024 + rb);
#pragma unroll
    for (int fm = 0; fm < 4; ++fm)
#pragma unroll
      for (int nf = 0; nf < 4; ++nf)
        acc[fm][nf] = MFMA(a[fm], b[nf], acc[fm][nf]);
  }

#pragma unroll
  for (int fm = 0; fm < 4; ++fm)
#pragma unroll
    for (int nf = 0; nf < 4; ++nf)
#pragma unroll
      for (int rr = 0; rr < 4; ++rr) {
        int row = tm + wr * 64 + fm * 16 + g * 4 + rr;
        int col = tn + wc * 64 + nf * 16 + lr;
        C[(size_t)row * 2048 + col] = acc[fm][nf][rr];
      }
}

// ---------- causal poly^4 attention (dual-group, pair-balanced; frozen) ----------
__global__ __launch_bounds__(512) void k_attn(const bf16* __restrict__ Q,
                                              const bf16* __restrict__ K,
                                              const bf16* __restrict__ Vt,
                                              bf16* __restrict__ O) {
  __shared__ __align__(16) char LDSC[131072];
  const int tid = threadIdx.x, w = tid >> 6, l = tid & 63;
  const int wg = w & 3, gp = w >> 2;
  const int lr = l & 15, g = l >> 4;
  const int pair = blockIdx.x >> 5;  // 0..7
  const int bh = blockIdx.x & 31;
  const size_t base = (size_t)bh * 2048 * 128;
  const int b_ = bh >> 4, h_ = bh & 15;
  const int GB = gp * 65536;  // group LDS base

  bf16x8 vones = {};
  if (lr == 0) {
#pragma unroll
    for (int j = 0; j < 8; ++j) vones[j] = (bf16)1.0f;
  }

#define STAGE_K(tt, buf)                                                  \
  {                                                                       \
    const bf16* kg = K + base + (size_t)(tt) * 64 * 128;                  \
    _Pragma("unroll") for (int r = 0; r < 4; ++r) {                       \
      int row = r * 16 + wg * 4 + (l >> 4);                               \
      int cc = l & 15;                                                    \
      GLD(kg + (row << 7) + ((cc ^ (row & 7)) << 3),                      \
          LDSC + GB + (buf) * 16384 + r * 4096 + wg * 1024);              \
    }                                                                     \
  }
#define STAGE_V(tt)                                                       \
  {                                                                       \
    const bf16* vg = Vt + base + (tt) * 64;                               \
    _Pragma("unroll") for (int r = 0; r < 4; ++r) {                       \
      int row = r * 32 + wg * 8 + (l >> 3);                               \
      int cc = l & 7;                                                     \
      GLD(vg + (size_t)row * 2048 + ((cc ^ (row & 7)) << 3),              \
          LDSC + GB + 32768 + r * 4096 + wg * 1024);                      \
    }                                                                     \
  }

  for (int seg = 0; seg < 2; ++seg) {
    const int qb = seg ? (15 - pair) : pair;
    const int qbase = qb * 128;
    const int nh = qb + 1;

    bf16x8 qf[2][4];
#pragma unroll
    for (int mi = 0; mi < 2; ++mi)
#pragma unroll
      for (int kc = 0; kc < 4; ++kc)
        qf[mi][kc] = *reinterpret_cast<const bf16x8*>(
            Q + base + (size_t)(qbase + wg * 32 + mi * 16 + lr) * 128 + kc * 32 + g * 8);

    f32x4 on[2][8] = {};
    f32x4 dn4[2] = {};

    __builtin_amdgcn_s_barrier();
    STAGE_K(gp, 0);

    for (int j = 0; j < nh; ++j) {
      const int t = 2 * j + gp;
      const int tnx = (j + 1 < nh) ? t + 2 : t;
      STAGE_V(t);
      STAGE_K(tnx, (j + 1) & 1);
      asm volatile("s_waitcnt vmcnt(8)" ::: "memory");
      __builtin_amdgcn_s_barrier();  // BAR1

      const bf16* kcur = (const bf16*)(LDSC + GB + (j & 1) * 16384);
      const bf16* vcur = (const bf16*)(LDSC + GB + 32768);
      bf16* Ps = (bf16*)(LDSC + GB + 49152);

      f32x4 s[2][4] = {};
      __builtin_amdgcn_s_setprio(1);
#pragma unroll
      for (int kc = 0; kc < 4; ++kc) {
        bf16x8 kb[4];
#pragma unroll
        for (int ni = 0; ni < 4; ++ni)
          kb[ni] = *reinterpret_cast<const bf16x8*>(
              kcur + ((ni * 16 + lr) << 7) + (((kc * 4 + g) ^ (lr & 7)) << 3));
#pragma unroll
        for (int mi = 0; mi < 2; ++mi)
#pragma unroll
          for (int ni = 0; ni < 4; ++ni)
            s[mi][ni] = MFMA(qf[mi][kc], kb[ni], s[mi][ni]);
      }
      __builtin_amdgcn_s_setprio(0);

#pragma unroll
      for (int mi = 0; mi < 2; ++mi) {
        const bool msk = (t * 64 + 63 > qbase + wg * 32 + mi * 16);
#pragma unroll
        for (int ni = 0; ni < 4; ++ni)
#pragma unroll
          for (int r = 0; r < 4; ++r) {
            int lrow = mi * 16 + g * 4 + r;
            float v = s[mi][ni][r];
            if (msk) {
              int qrow = qbase + wg * 32 + lrow;
              int col = t * 64 + ni * 16 + lr;
              v = (col <= qrow) ? v : 0.f;
            }
            float v2 = v * v, v4 = v2 * v2;
            Ps[((wg * 32 + lrow) << 6) +
               (((ni * 2 + (lr >> 3)) ^ (lrow & 7)) << 3) + (lr & 7)] = (bf16)v4;
          }
      }

      asm volatile("s_waitcnt vmcnt(4)" ::: "memory");
      __builtin_amdgcn_s_barrier();  // BAR2

      __builtin_amdgcn_s_setprio(1);
#pragma unroll
      for (int k2 = 0; k2 < 2; ++k2) {
        bf16x8 pa[2];
#pragma unroll
        for (int mi = 0; mi < 2; ++mi)
          pa[mi] = *reinterpret_cast<const bf16x8*>(
              Ps + ((wg * 32 + mi * 16 + lr) << 6) + (((k2 * 4 + g) ^ (lr & 7)) << 3));
        dn4[0] = MFMA(pa[0], vones, dn4[0]);
        dn4[1] = MFMA(pa[1], vones, dn4[1]);
#pragma unroll
        for (int ni = 0; ni < 8; ++ni) {
          bf16x8 vbf = *reinterpret_cast<const bf16x8*>(
              vcur + ((ni * 16 + lr) << 6) + (((k2 * 4 + g) ^ (lr & 7)) << 3));
          on[0][ni] = MFMA(pa[0], vbf, on[0][ni]);
          on[1][ni] = MFMA(pa[1], vbf, on[1][ni]);
        }
      }
      __builtin_amdgcn_s_setprio(0);
      __builtin_amdgcn_s_barrier();  // BAR3
    }

    asm volatile("s_waitcnt vmcnt(0)" ::: "memory");
    __builtin_amdgcn_s_barrier();

    if (gp == 1) {
      f32x4* dst = (f32x4*)(LDSC + (size_t)(tid & 255) * 288);
#pragma unroll
      for (int mi = 0; mi < 2; ++mi)
#pragma unroll
        for (int ni = 0; ni < 8; ++ni) dst[mi * 8 + ni] = on[mi][ni];
      dst[16] = dn4[0];
      dst[17] = dn4[1];
    }
    __builtin_amdgcn_s_barrier();
    if (gp == 0) {
      const f32x4* src = (const f32x4*)(LDSC + (size_t)tid * 288);
#pragma unroll
      for (int mi = 0; mi < 2; ++mi)
#pragma unroll
        for (int ni = 0; ni < 8; ++ni) on[mi][ni] += src[mi * 8 + ni];
      dn4[0] += src[16];
      dn4[1] += src[17];
#pragma unroll
      for (int mi = 0; mi < 2; ++mi)
#pragma unroll
        for (int r = 0; r < 4; ++r) {
          float d = __shfl(dn4[mi][r], l & 48);
          float inv = 1.0f / fmaxf(d, 1e-6f);
          int row = qbase + wg * 32 + mi * 16 + g * 4 + r;
#pragma unroll
          for (int ni = 0; ni < 8; ++ni)
            O[((size_t)b_ * 2048 + row) * 2048 + h_ * 128 + ni * 16 + lr] =
                (bf16)(on[mi][ni][r] * inv);
        }
    }
  }
#undef STAGE_K
#undef STAGE_V
}

extern "C" void kernel_launch(void* const* d_in, const int* in_sizes, int n_in,
                              void* d_out, int out_size, void* d_ws, size_t ws_size,
                              hipStream_t stream) {
  const float* x  = (const float*)d_in[0];
  const float* Wq = (const float*)d_in[1];
  const float* Wk = (const float*)d_in[2];
  const float* Wv = (const float*)d_in[3];
  const float* Wo = (const float*)d_in[4];
  float* out = (float*)d_out;

  char* p = (char*)d_ws;
  bf16* xb   = (bf16*)p; p += (size_t)8388608 * 2;
  bf16* wqkv = (bf16*)p; p += (size_t)12582912 * 2;
  bf16* wob  = (bf16*)p; p += (size_t)4194304 * 2;
  bf16* Qp   = (bf16*)p; p += (size_t)8388608 * 2;
  bf16* Kp   = (bf16*)p; p += (size_t)8388608 * 2;
  bf16* Vt   = (bf16*)p; p += (size_t)8388608 * 2;
  bf16* Ob   = (bf16*)p; p += (size_t)8388608 * 2;
  float* ct  = (float*)p; p += (size_t)131072 * 4;
  float* st  = (float*)p; p += (size_t)131072 * 4;

  k_prep<<<25088, 256, 0, stream>>>(x, Wq, Wk, Wv, Wo, xb, wqkv, wob, ct, st);

  k_gemm_qkv<<<dim3(48, 16), 256, 0, stream>>>(xb, wqkv, Qp, Kp, Vt, ct, st);

  k_attn<<<256, 512, 0, stream>>>(Qp, Kp, Vt, Ob);

  k_gemm_out<<<dim3(16, 32), 256, 0, stream>>>(Ob, wob, out);
}